// Round 4
// baseline (295.715 us; speedup 1.0000x reference)
//
#include <hip/hip_runtime.h>
#include <stdint.h>

#define S_ 2048
#define H_ 16

typedef short s16x8 __attribute__((ext_vector_type(8)));
typedef float f32x4 __attribute__((ext_vector_type(4)));
typedef float f32x16 __attribute__((ext_vector_type(16)));

__device__ __forceinline__ ushort f2bf(float f) {
    union { float f; uint32_t u; } v; v.f = f;
    uint32_t r = v.u + 0x7fffu + ((v.u >> 16) & 1u);
    return (ushort)(r >> 16);
}
// v_cvt_pk_bf16_f32: dst.lo = bf16(a), dst.hi = bf16(b) (RNE, same as f2bf)
__device__ __forceinline__ uint32_t cvtpk(float a, float b) {
    uint32_t r;
    asm("v_cvt_pk_bf16_f32 %0, %1, %2" : "=v"(r) : "v"(a), "v"(b));
    return r;
}
// permlane32_swap: a' = {a.lo32, b.lo32}, b' = {a.hi32, b.hi32}
__device__ __forceinline__ void plswap(uint32_t& a, uint32_t& b) {
    auto r = __builtin_amdgcn_permlane32_swap((int)a, (int)b, false, false);
    a = (uint32_t)r[0];
    b = (uint32_t)r[1];
}
__device__ __forceinline__ float xmax32(float x) {  // max with lane^32 partner
    uint32_t a = __float_as_uint(x), b = a;
    plswap(a, b);
    return fmaxf(__uint_as_float(a), __uint_as_float(b));
}
__device__ __forceinline__ float xadd32(float x) {  // sum with lane^32 partner
    uint32_t a = __float_as_uint(x), b = a;
    plswap(a, b);
    return __uint_as_float(a) + __uint_as_float(b);
}
__device__ __forceinline__ float exp2_fast(float x) {
    float r;
    asm("v_exp_f32 %0, %1" : "=v"(r) : "v"(x));
    return r;
}

// async global->LDS, 16B per lane. LDS dest is wave-uniform base + lane*16.
__device__ __forceinline__ void gld16(ushort* lds, const ushort* g) {
    auto* gp = reinterpret_cast<uint32_t __attribute__((address_space(1)))*>(
        reinterpret_cast<uintptr_t>(g));
    auto* lp = reinterpret_cast<uint32_t __attribute__((address_space(3)))*>(
        reinterpret_cast<uintptr_t>(lds));
    __builtin_amdgcn_global_load_lds(gp, lp, 16, 0, 0);
}

// ---- X fp32 -> bf16 ----
__global__ void cast_bf16(const float* __restrict__ src, ushort* __restrict__ dst) {
    size_t i = ((size_t)blockIdx.x * 256 + threadIdx.x) * 8;
    float4 x = *(const float4*)(src + i);
    float4 y = *(const float4*)(src + i + 4);
    s16x8 r;
    r[0] = (short)f2bf(x.x); r[1] = (short)f2bf(x.y);
    r[2] = (short)f2bf(x.z); r[3] = (short)f2bf(x.w);
    r[4] = (short)f2bf(y.x); r[5] = (short)f2bf(y.y);
    r[6] = (short)f2bf(y.z); r[7] = (short)f2bf(y.w);
    *(s16x8*)(dst + i) = r;
}

// ---- weight prep: dst[n*1024+k] = bf16(src[k*1024+n]) ----
__global__ void transpose_k4(const float* __restrict__ s0, const float* __restrict__ s1,
                             const float* __restrict__ s2, const float* __restrict__ s3,
                             ushort* __restrict__ d0, ushort* __restrict__ d1,
                             ushort* __restrict__ d2, ushort* __restrict__ d3) {
    const int z = blockIdx.z;
    const float* src = (z == 0) ? s0 : (z == 1) ? s1 : (z == 2) ? s2 : s3;
    ushort* dst      = (z == 0) ? d0 : (z == 1) ? d1 : (z == 2) ? d2 : d3;
    __shared__ ushort t[32][33];
    int bx = blockIdx.x * 32, by = blockIdx.y * 32;
    int x = threadIdx.x;
    for (int y = threadIdx.y; y < 32; y += 8)
        t[y][x] = f2bf(src[(size_t)(by + y) * 1024 + bx + x]);
    __syncthreads();
    for (int y = threadIdx.y; y < 32; y += 8)
        dst[(size_t)(bx + y) * 1024 + by + x] = t[x][y];
}

// ---------------- GEMM: C[m,n] = A[M,K] @ Bt[N,K]^T + bias(fp32) ------------
// mode 0: FP32 out[m*1024+n]
// mode 1: Q:  bf16 out[((b*16+h)*2048+s)*64+d] = v * 0.125 * log2(e)  (exp2 domain)
// mode 2: K:  bf16 out[((b*16+h)*2048+s)*64+d] = v
// mode 3: Vt: bf16 out[((b*16+h)*64+d)*2048+s] = v  (via LDS transpose, coalesced)
__global__ void gemm_bt(const ushort* __restrict__ A,
                        const ushort* __restrict__ Bt0, const ushort* __restrict__ Bt1,
                        const ushort* __restrict__ Bt2,
                        const float* __restrict__ bi0, const float* __restrict__ bi1,
                        const float* __restrict__ bi2,
                        void* __restrict__ o0, void* __restrict__ o1,
                        void* __restrict__ o2,
                        int mode0) {
    const int z = blockIdx.z;
    const ushort* Bt  = (z == 0) ? Bt0 : (z == 1) ? Bt1 : Bt2;
    const float* bia  = (z == 0) ? bi0 : (z == 1) ? bi1 : bi2;
    void* out         = (z == 0) ? o0  : (z == 1) ? o1  : o2;
    const int mode = mode0 + z;

    __shared__ __align__(16) ushort SMEM[2][4096];  // Asm | Bsm, 16KB contiguous
    ushort* Asm = &SMEM[0][0];
    ushort* Bsm = &SMEM[1][0];

    const int t = threadIdx.x;
    const int lane = t & 63, w = t >> 6;
    const int wm = w >> 1, wn = w & 1;
    const int quad = lane >> 4, l16 = lane & 15;
    const int m0 = blockIdx.y * 128, n0 = blockIdx.x * 128;
    const int K = 1024;

    const f32x4 FZ = {0.f, 0.f, 0.f, 0.f};
    f32x4 acc[4][4];
#pragma unroll
    for (int i = 0; i < 4; i++)
#pragma unroll
        for (int j = 0; j < 4; j++) acc[i][j] = FZ;

    const ushort* Ap = A  + (size_t)(m0 + (t >> 2)) * K + (t & 3) * 8;
    const ushort* Bp = Bt + (size_t)(n0 + (t >> 2)) * K + (t & 3) * 8;
    ushort* AsmW = Asm + w * 512;
    ushort* BsmW = Bsm + w * 512;

    for (int kt = 0; kt < K / 32; ++kt) {
        __syncthreads();
        gld16(AsmW,        Ap + kt * 32);
        gld16(AsmW + 2048, Ap + (size_t)64 * K + kt * 32);
        gld16(BsmW,        Bp + kt * 32);
        gld16(BsmW + 2048, Bp + (size_t)64 * K + kt * 32);
        __syncthreads();

        s16x8 a[4], b[4];
#pragma unroll
        for (int i = 0; i < 4; i++) {
            int row = wm * 64 + i * 16 + l16;
            a[i] = *(const s16x8*)((const char*)Asm + row * 64 + quad * 16);
        }
#pragma unroll
        for (int j = 0; j < 4; j++) {
            int row = wn * 64 + j * 16 + l16;
            b[j] = *(const s16x8*)((const char*)Bsm + row * 64 + quad * 16);
        }
#pragma unroll
        for (int i = 0; i < 4; i++)
#pragma unroll
            for (int j = 0; j < 4; j++)
                acc[i][j] = __builtin_amdgcn_mfma_f32_16x16x32_bf16(a[i], b[j], acc[i][j], 0, 0, 0);
    }

    if (mode == 3) {
        // V^T epilogue: transpose the 128x128 tile through LDS (XOR-swizzled),
        // then coalesced 16B row stores. Replaces 64 scalar stores at 4KB stride.
        ushort* T = Asm;  // 16KB: holds one 64(n) x 128(m) half-tile
        const int b_ = m0 >> 11;
        const int s_base = m0 & 2047;
        __syncthreads();  // last k-iter LDS reads done
#pragma unroll
        for (int half = 0; half < 2; ++half) {
            if (wn == half) {
#pragma unroll
                for (int j = 0; j < 4; j++) {
                    int nl = j * 16 + l16;
                    float bv = bia[n0 + half * 64 + nl];
#pragma unroll
                    for (int i = 0; i < 4; i++) {
#pragma unroll
                        for (int r = 0; r < 4; r++) {
                            int ml = wm * 64 + i * 16 + quad * 4 + r;
                            T[nl * 128 + (ml ^ ((nl & 15) << 3))] = f2bf(acc[i][j][r] + bv);
                        }
                    }
                }
            }
            __syncthreads();
            {
                int row = t >> 2, cg = (t & 3) * 32;
                int ng = n0 + half * 64 + row;
                int h = ng >> 6, d = ng & 63;
                ushort* op = (ushort*)out + ((size_t)((b_ * 16 + h) * 64 + d)) * 2048 + s_base + cg;
#pragma unroll
                for (int c = 0; c < 4; c++) {
                    int col = (cg + c * 8) ^ ((row & 15) << 3);
                    *(s16x8*)(op + c * 8) = *(const s16x8*)(T + row * 128 + col);
                }
            }
            __syncthreads();
        }
        return;
    }

#pragma unroll
    for (int j = 0; j < 4; j++) {
        int n = n0 + wn * 64 + j * 16 + l16;
        float bv = bia[n];
#pragma unroll
        for (int i = 0; i < 4; i++) {
#pragma unroll
            for (int r = 0; r < 4; r++) {
                int m = m0 + wm * 64 + i * 16 + quad * 4 + r;
                float v = acc[i][j][r] + bv;
                if (mode == 0) {
                    ((float*)out)[(size_t)m * 1024 + n] = v;
                } else {
                    int b_ = m >> 11, s = m & 2047;
                    int h = n >> 6, d = n & 63;
                    if (mode == 1)  // 0.125 * log2(e): attn softmax runs in exp2 domain
                        ((ushort*)out)[((size_t)(b_ * 16 + h) * 2048 + s) * 64 + d] = f2bf(v * 0.18033688011112042f);
                    else
                        ((ushort*)out)[((size_t)(b_ * 16 + h) * 2048 + s) * 64 + d] = f2bf(v);
                }
            }
        }
    }
}

// ---------------- MFMA flash attention, swapped-operand 32x32, split-K ----------
// grid: 1024 flat (XCD-swizzled), 256 threads = 4 waves. Wave w: q-tile (w&1),
// k-half (w>>1). Softmax in exp2 domain (Q pre-scaled by 0.125*log2e).
// Per k-tile: QK^T mfmas -> issue all 8 V loads + all 8 next-K loads (latency
// hidden under softmax) -> softmax (cvt_pk + permlane32_swap pack, no LDS) -> PV.
// XCD swizzle: all 32 q-blocks of one bh land on one XCD -> K/V L2-resident.
#define MFMA32(a, b, c) __builtin_amdgcn_mfma_f32_32x32x16_bf16(a, b, c, 0, 0, 0)

#define ABODY(KT, PKT, A0_,A1_,A2_,A3_,A4_,A5_,A6_,A7_, B0_,B1_,B2_,B3_,B4_,B5_,B6_,B7_) { \
    f32x16 _s0 = Z16, _s1 = Z16;                                                   \
    _s0 = MFMA32(A0_, qf[0], _s0); _s0 = MFMA32(A1_, qf[1], _s0);                  \
    _s0 = MFMA32(A2_, qf[2], _s0); _s0 = MFMA32(A3_, qf[3], _s0);                  \
    _s1 = MFMA32(A4_, qf[0], _s1); _s1 = MFMA32(A5_, qf[1], _s1);                  \
    _s1 = MFMA32(A6_, qf[2], _s1); _s1 = MFMA32(A7_, qf[3], _s1);                  \
    const ushort* _vpt = vp + (KT) * 64;                                           \
    s16x8 _v0 = *(const s16x8*)(_vpt);                                             \
    s16x8 _v1 = *(const s16x8*)(_vpt + 16);                                        \
    s16x8 _v2 = *(const s16x8*)(_vpt + 32);                                        \
    s16x8 _v3 = *(const s16x8*)(_vpt + 48);                                        \
    s16x8 _v4 = *(const s16x8*)(_vpt + 32 * 2048);                                 \
    s16x8 _v5 = *(const s16x8*)(_vpt + 32 * 2048 + 16);                            \
    s16x8 _v6 = *(const s16x8*)(_vpt + 32 * 2048 + 32);                            \
    s16x8 _v7 = *(const s16x8*)(_vpt + 32 * 2048 + 48);                            \
    { const ushort* _np = kp + (size_t)(PKT) * 4096;                               \
      B0_ = *(const s16x8*)(_np);        B1_ = *(const s16x8*)(_np + 16);          \
      B2_ = *(const s16x8*)(_np + 32);   B3_ = *(const s16x8*)(_np + 48);          \
      B4_ = *(const s16x8*)(_np + 2048); B5_ = *(const s16x8*)(_np + 2048 + 16);   \
      B6_ = *(const s16x8*)(_np + 2048 + 32); B7_ = *(const s16x8*)(_np + 2048 + 48); } \
    float _m0 = fmaxf(_s0[0], _s1[0]), _m1 = fmaxf(_s0[1], _s1[1]);                \
    float _m2 = fmaxf(_s0[2], _s1[2]), _m3 = fmaxf(_s0[3], _s1[3]);                \
    _Pragma("unroll")                                                              \
    for (int _r = 4; _r < 16; _r += 4) {                                           \
        _m0 = fmaxf(_m0, fmaxf(_s0[_r],     _s1[_r]));                             \
        _m1 = fmaxf(_m1, fmaxf(_s0[_r + 1], _s1[_r + 1]));                         \
        _m2 = fmaxf(_m2, fmaxf(_s0[_r + 2], _s1[_r + 2]));                         \
        _m3 = fmaxf(_m3, fmaxf(_s0[_r + 3], _s1[_r + 3]));                         \
    }                                                                              \
    float _mx = fmaxf(fmaxf(_m0, _m1), fmaxf(_m2, _m3));                           \
    _mx = xmax32(_mx);                                                             \
    float _mnew = fmaxf(m_run, _mx);                                               \
    float _alpha = exp2_fast(m_run - _mnew);                                       \
    m_run = _mnew;                                                                 \
    float _ra = 0.f, _rb = 0.f;                                                    \
    _Pragma("unroll")                                                              \
    for (int _r = 0; _r < 16; _r++) {                                              \
        _s0[_r] = exp2_fast(_s0[_r] - _mnew); _ra += _s0[_r];                      \
        _s1[_r] = exp2_fast(_s1[_r] - _mnew); _rb += _s1[_r];                      \
    }                                                                              \
    float _rs = xadd32(_ra + _rb);                                                 \
    l_run = l_run * _alpha + _rs;                                                  \
    _Pragma("unroll")                                                              \
    for (int _r = 0; _r < 16; _r++) { o0[_r] *= _alpha; o1[_r] *= _alpha; }        \
    {                                                                              \
        uint32_t _u0 = cvtpk(_s0[0], _s0[1]), _u2 = cvtpk(_s0[4], _s0[5]);         \
        plswap(_u0, _u2);                                                          \
        uint32_t _u1 = cvtpk(_s0[2], _s0[3]), _u3 = cvtpk(_s0[6], _s0[7]);         \
        plswap(_u1, _u3);                                                          \
        uint32_t _w0 = cvtpk(_s0[8], _s0[9]), _w2 = cvtpk(_s0[12], _s0[13]);       \
        plswap(_w0, _w2);                                                          \
        uint32_t _w1 = cvtpk(_s0[10], _s0[11]), _w3 = cvtpk(_s0[14], _s0[15]);     \
        plswap(_w1, _w3);                                                          \
        union { uint32_t u[4]; s16x8 h; } _F0, _F1;                                \
        _F0.u[0] = _u0; _F0.u[1] = _u1; _F0.u[2] = _u2; _F0.u[3] = _u3;            \
        _F1.u[0] = _w0; _F1.u[1] = _w1; _F1.u[2] = _w2; _F1.u[3] = _w3;            \
        o0 = MFMA32(_v0, _F0.h, o0); o1 = MFMA32(_v4, _F0.h, o1);                  \
        o0 = MFMA32(_v1, _F1.h, o0); o1 = MFMA32(_v5, _F1.h, o1);                  \
    }                                                                              \
    {                                                                              \
        uint32_t _u0 = cvtpk(_s1[0], _s1[1]), _u2 = cvtpk(_s1[4], _s1[5]);         \
        plswap(_u0, _u2);                                                          \
        uint32_t _u1 = cvtpk(_s1[2], _s1[3]), _u3 = cvtpk(_s1[6], _s1[7]);         \
        plswap(_u1, _u3);                                                          \
        uint32_t _w0 = cvtpk(_s1[8], _s1[9]), _w2 = cvtpk(_s1[12], _s1[13]);       \
        plswap(_w0, _w2);                                                          \
        uint32_t _w1 = cvtpk(_s1[10], _s1[11]), _w3 = cvtpk(_s1[14], _s1[15]);     \
        plswap(_w1, _w3);                                                          \
        union { uint32_t u[4]; s16x8 h; } _F0, _F1;                                \
        _F0.u[0] = _u0; _F0.u[1] = _u1; _F0.u[2] = _u2; _F0.u[3] = _u3;            \
        _F1.u[0] = _w0; _F1.u[1] = _w1; _F1.u[2] = _w2; _F1.u[3] = _w3;            \
        o0 = MFMA32(_v2, _F0.h, o0); o1 = MFMA32(_v6, _F0.h, o1);                  \
        o0 = MFMA32(_v3, _F1.h, o0); o1 = MFMA32(_v7, _F1.h, o1);                  \
    }                                                                              \
}

__global__ __launch_bounds__(256, 2) void attn(const ushort* __restrict__ q_ws,
                                               const ushort* __restrict__ k_ws,
                                               const ushort* __restrict__ vt_ws,
                                               ushort* __restrict__ ctx) {
    __shared__ float part[2][64][33];
    __shared__ float pml[2][64][2];
    __shared__ float obuf[2][32][65];

    const int t = threadIdx.x, lane = t & 63, w = t >> 6;
    const int l32 = lane & 31, hi = lane >> 5;
    const int qt = w & 1, khalf = w >> 1;

    // XCD swizzle: xcd = bid&7 (round-robin dispatch); bh = xcd + 8*(j>>5).
    // All 32 q-blocks of a bh share one XCD's L2 (1MB K/V, L2-resident).
    const int bid = blockIdx.x;
    const int j_ = bid >> 3;
    const int bh = (bid & 7) + 8 * (j_ >> 5);
    const int q0 = (j_ & 31) * 64 + qt * 32;

    const ushort* Qg = q_ws + (size_t)bh * S_ * 64;
    const ushort* Kg = k_ws + (size_t)bh * S_ * 64;
    const ushort* Vg = vt_ws + (size_t)bh * 64 * S_;

    // Q fragments: B-operand of QK^T. col=lane&31 -> q=q0+l32; k=8*hi+e -> d.
    s16x8 qf[4];
#pragma unroll
    for (int dc = 0; dc < 4; dc++)
        qf[dc] = *(const s16x8*)&Qg[(size_t)(q0 + l32) * 64 + dc * 16 + hi * 8];

    const f32x16 Z16 = {0.f,0.f,0.f,0.f,0.f,0.f,0.f,0.f,0.f,0.f,0.f,0.f,0.f,0.f,0.f,0.f};
    f32x16 o0 = Z16, o1 = Z16;            // O^T: o0 = d 0..31, o1 = d 32..63
    float m_run = -1e30f, l_run = 0.f;

    const ushort* kp = Kg + (size_t)l32 * 64 + hi * 8;
    const ushort* vp = Vg + (size_t)l32 * 2048 + hi * 8;

    const int kbeg = khalf * 16;
    s16x8 ka0, ka1, ka2, ka3, ka4, ka5, ka6, ka7;
    s16x8 kb0, kb1, kb2, kb3, kb4, kb5, kb6, kb7;
    {   // preload first K tile
        const ushort* np = kp + (size_t)kbeg * 4096;
        ka0 = *(const s16x8*)(np);        ka1 = *(const s16x8*)(np + 16);
        ka2 = *(const s16x8*)(np + 32);   ka3 = *(const s16x8*)(np + 48);
        ka4 = *(const s16x8*)(np + 2048); ka5 = *(const s16x8*)(np + 2048 + 16);
        ka6 = *(const s16x8*)(np + 2048 + 32); ka7 = *(const s16x8*)(np + 2048 + 48);
    }
    for (int it = 0; it < 8; ++it) {
        const int kt0 = kbeg + it * 2;
        ABODY(kt0,     kt0 + 1, ka0,ka1,ka2,ka3,ka4,ka5,ka6,ka7, kb0,kb1,kb2,kb3,kb4,kb5,kb6,kb7);
        ABODY(kt0 + 1, kt0 + 2, kb0,kb1,kb2,kb3,kb4,kb5,kb6,kb7, ka0,ka1,ka2,ka3,ka4,ka5,ka6,ka7);
        // last prefetch (tile kbeg+16) reads past this bh's K -> still inside ws, unused
    }

    // ---- split-K merge: khalf=1 waves publish partials, khalf=0 waves combine
    if (khalf == 1) {
#pragma unroll
        for (int r = 0; r < 16; r++) {
            part[qt][lane][r]      = o0[r];
            part[qt][lane][16 + r] = o1[r];
        }
        pml[qt][lane][0] = m_run;
        pml[qt][lane][1] = l_run;
    }
    __syncthreads();
    if (khalf == 1) return;

    {
        float m2 = pml[qt][lane][0], l2 = pml[qt][lane][1];
        float mm = fmaxf(m_run, m2);
        float a1 = exp2_fast(m_run - mm), a2 = exp2_fast(m2 - mm);
#pragma unroll
        for (int r = 0; r < 16; r++) {
            o0[r] = o0[r] * a1 + part[qt][lane][r] * a2;
            o1[r] = o1[r] * a1 + part[qt][lane][16 + r] * a2;
        }
        l_run = l_run * a1 + l2 * a2;
    }

    // ---- epilogue: O^T -> per-wave LDS transpose -> row-major 16B stores
    float inv = 1.0f / l_run;
#pragma unroll
    for (int r = 0; r < 16; r++) {
        int d0 = (r & 3) + 8 * (r >> 2) + 4 * hi;
        obuf[qt][l32][d0]      = o0[r] * inv;
        obuf[qt][l32][32 + d0] = o1[r] * inv;
    }
    // obuf[qt] is private to this wave: wave-level LDS drain suffices
    asm volatile("s_waitcnt lgkmcnt(0)" ::: "memory");
    __builtin_amdgcn_sched_barrier(0);
    int b_ = bh >> 4, h = bh & 15;
    ushort* gp = ctx + ((size_t)(b_ * 2048 + q0 + l32)) * 1024 + h * 64 + hi * 32;
#pragma unroll
    for (int c = 0; c < 4; c++) {
        s16x8 vv;
#pragma unroll
        for (int j = 0; j < 8; j++) vv[j] = (short)f2bf(obuf[qt][l32][hi * 32 + c * 8 + j]);
        *(s16x8*)(gp + c * 8) = vv;
    }
}

extern "C" void kernel_launch(void* const* d_in, const int* in_sizes, int n_in,
                              void* d_out, int out_size, void* d_ws, size_t ws_size,
                              hipStream_t stream) {
    const float* X  = (const float*)d_in[0];
    const float* Wq = (const float*)d_in[1];
    const float* bq = (const float*)d_in[2];
    const float* Wk = (const float*)d_in[3];
    const float* bk = (const float*)d_in[4];
    const float* Wv = (const float*)d_in[5];
    const float* bv = (const float*)d_in[6];
    const float* Wo = (const float*)d_in[7];
    const float* bo = (const float*)d_in[8];
    float* out = (float*)d_out;

    // ws (MiB): wtq@0(2) wtk@2(2) wtv@4(2) wto@6(2) qws@8(8) kws@16(8)
    // ctx@24(8) = 32 MiB. d_out (16 MiB fp32) hosts V^T bf16 @0 (8 MiB) and
    // Xbf16 @8MiB (8 MiB): both dead before the final GEMM overwrites d_out.
    char* ws = (char*)d_ws;
    ushort* wtq  = (ushort*)(ws);
    ushort* wtk  = (ushort*)(ws + ((size_t)2 << 20));
    ushort* wtv  = (ushort*)(ws + ((size_t)4 << 20));
    ushort* wto  = (ushort*)(ws + ((size_t)6 << 20));
    ushort* qws  = (ushort*)(ws + ((size_t)8 << 20));
    ushort* kws  = (ushort*)(ws + ((size_t)16 << 20));
    ushort* ctx  = (ushort*)(ws + ((size_t)24 << 20));
    ushort* vtws = (ushort*)d_out;
    ushort* xbf  = (ushort*)d_out + ((size_t)4 << 20);  // +8 MiB

    transpose_k4<<<dim3(32, 32, 4), dim3(32, 8), 0, stream>>>(Wq, Wk, Wv, Wo,
                                                              wtq, wtk, wtv, wto);
    cast_bf16<<<2048, 256, 0, stream>>>(X, xbf);

    gemm_bt<<<dim3(8, 32, 3), 256, 0, stream>>>(xbf, wtq, wtk, wtv, bq, bk, bv,
                                                qws, kws, vtws, 1);

    attn<<<dim3(1024), 256, 0, stream>>>(qws, kws, vtws, ctx);

    gemm_bt<<<dim3(8, 32, 1), 256, 0, stream>>>(ctx, wto, wto, wto, bo, bo, bo,
                                                out, out, out, 0);
}

// Round 5
// 207.721 us; speedup vs baseline: 1.4236x; 1.4236x over previous
//
#include <hip/hip_runtime.h>
#include <stdint.h>

#define S_ 2048
#define H_ 16

typedef short s16x8 __attribute__((ext_vector_type(8)));
typedef float f32x4 __attribute__((ext_vector_type(4)));
typedef float f32x16 __attribute__((ext_vector_type(16)));

__device__ __forceinline__ ushort f2bf(float f) {
    union { float f; uint32_t u; } v; v.f = f;
    uint32_t r = v.u + 0x7fffu + ((v.u >> 16) & 1u);
    return (ushort)(r >> 16);
}
// v_cvt_pk_bf16_f32: dst.lo = bf16(a), dst.hi = bf16(b) (RNE, same as f2bf)
__device__ __forceinline__ uint32_t cvtpk(float a, float b) {
    uint32_t r;
    asm("v_cvt_pk_bf16_f32 %0, %1, %2" : "=v"(r) : "v"(a), "v"(b));
    return r;
}
// permlane32_swap: a' = {a.lo32, b.lo32}, b' = {a.hi32, b.hi32}
__device__ __forceinline__ void plswap(uint32_t& a, uint32_t& b) {
    auto r = __builtin_amdgcn_permlane32_swap((int)a, (int)b, false, false);
    a = (uint32_t)r[0];
    b = (uint32_t)r[1];
}
__device__ __forceinline__ float xmax32(float x) {  // max with lane^32 partner
    uint32_t a = __float_as_uint(x), b = a;
    plswap(a, b);
    return fmaxf(__uint_as_float(a), __uint_as_float(b));
}
__device__ __forceinline__ float xadd32(float x) {  // sum with lane^32 partner
    uint32_t a = __float_as_uint(x), b = a;
    plswap(a, b);
    return __uint_as_float(a) + __uint_as_float(b);
}
__device__ __forceinline__ float exp2_fast(float x) {
    float r;
    asm("v_exp_f32 %0, %1" : "=v"(r) : "v"(x));
    return r;
}

// async global->LDS, 16B per lane. LDS dest is wave-uniform base + lane*16.
__device__ __forceinline__ void gld16(ushort* lds, const ushort* g) {
    auto* gp = reinterpret_cast<uint32_t __attribute__((address_space(1)))*>(
        reinterpret_cast<uintptr_t>(g));
    auto* lp = reinterpret_cast<uint32_t __attribute__((address_space(3)))*>(
        reinterpret_cast<uintptr_t>(lds));
    __builtin_amdgcn_global_load_lds(gp, lp, 16, 0, 0);
}

// ---- X fp32 -> bf16 ----
__global__ void cast_bf16(const float* __restrict__ src, ushort* __restrict__ dst) {
    size_t i = ((size_t)blockIdx.x * 256 + threadIdx.x) * 8;
    float4 x = *(const float4*)(src + i);
    float4 y = *(const float4*)(src + i + 4);
    s16x8 r;
    r[0] = (short)f2bf(x.x); r[1] = (short)f2bf(x.y);
    r[2] = (short)f2bf(x.z); r[3] = (short)f2bf(x.w);
    r[4] = (short)f2bf(y.x); r[5] = (short)f2bf(y.y);
    r[6] = (short)f2bf(y.z); r[7] = (short)f2bf(y.w);
    *(s16x8*)(dst + i) = r;
}

// ---- weight prep: dst[n*1024+k] = bf16(src[k*1024+n]) ----
__global__ void transpose_k4(const float* __restrict__ s0, const float* __restrict__ s1,
                             const float* __restrict__ s2, const float* __restrict__ s3,
                             ushort* __restrict__ d0, ushort* __restrict__ d1,
                             ushort* __restrict__ d2, ushort* __restrict__ d3) {
    const int z = blockIdx.z;
    const float* src = (z == 0) ? s0 : (z == 1) ? s1 : (z == 2) ? s2 : s3;
    ushort* dst      = (z == 0) ? d0 : (z == 1) ? d1 : (z == 2) ? d2 : d3;
    __shared__ ushort t[32][33];
    int bx = blockIdx.x * 32, by = blockIdx.y * 32;
    int x = threadIdx.x;
    for (int y = threadIdx.y; y < 32; y += 8)
        t[y][x] = f2bf(src[(size_t)(by + y) * 1024 + bx + x]);
    __syncthreads();
    for (int y = threadIdx.y; y < 32; y += 8)
        dst[(size_t)(bx + y) * 1024 + by + x] = t[x][y];
}

// ---------------- GEMM: C[m,n] = A[M,K] @ Bt[N,K]^T + bias(fp32) ------------
// mode 0: FP32 out[m*1024+n]
// mode 1: Q:  bf16 out[((b*16+h)*2048+s)*64+d] = v * 0.125 * log2(e)  (exp2 domain)
// mode 2: K:  bf16 out[((b*16+h)*2048+s)*64+d] = v
// mode 3: Vt: bf16 out[((b*16+h)*64+d)*2048+s] = v  (via LDS transpose, coalesced)
__global__ void gemm_bt(const ushort* __restrict__ A,
                        const ushort* __restrict__ Bt0, const ushort* __restrict__ Bt1,
                        const ushort* __restrict__ Bt2,
                        const float* __restrict__ bi0, const float* __restrict__ bi1,
                        const float* __restrict__ bi2,
                        void* __restrict__ o0, void* __restrict__ o1,
                        void* __restrict__ o2,
                        int mode0) {
    const int z = blockIdx.z;
    const ushort* Bt  = (z == 0) ? Bt0 : (z == 1) ? Bt1 : Bt2;
    const float* bia  = (z == 0) ? bi0 : (z == 1) ? bi1 : bi2;
    void* out         = (z == 0) ? o0  : (z == 1) ? o1  : o2;
    const int mode = mode0 + z;

    __shared__ __align__(16) ushort SMEM[2][4096];  // Asm | Bsm
    ushort* Asm = &SMEM[0][0];
    ushort* Bsm = &SMEM[1][0];

    const int t = threadIdx.x;
    const int lane = t & 63, w = t >> 6;
    const int wm = w >> 1, wn = w & 1;
    const int quad = lane >> 4, l16 = lane & 15;
    const int m0 = blockIdx.y * 128, n0 = blockIdx.x * 128;
    const int K = 1024;

    const f32x4 FZ = {0.f, 0.f, 0.f, 0.f};
    f32x4 acc[4][4];
#pragma unroll
    for (int i = 0; i < 4; i++)
#pragma unroll
        for (int j = 0; j < 4; j++) acc[i][j] = FZ;

    const ushort* Ap = A  + (size_t)(m0 + (t >> 2)) * K + (t & 3) * 8;
    const ushort* Bp = Bt + (size_t)(n0 + (t >> 2)) * K + (t & 3) * 8;
    ushort* AsmW = Asm + w * 512;
    ushort* BsmW = Bsm + w * 512;

    for (int kt = 0; kt < K / 32; ++kt) {
        __syncthreads();
        gld16(AsmW,        Ap + kt * 32);
        gld16(AsmW + 2048, Ap + (size_t)64 * K + kt * 32);
        gld16(BsmW,        Bp + kt * 32);
        gld16(BsmW + 2048, Bp + (size_t)64 * K + kt * 32);
        __syncthreads();

        s16x8 a[4], b[4];
#pragma unroll
        for (int i = 0; i < 4; i++) {
            int row = wm * 64 + i * 16 + l16;
            a[i] = *(const s16x8*)((const char*)Asm + row * 64 + quad * 16);
        }
#pragma unroll
        for (int j = 0; j < 4; j++) {
            int row = wn * 64 + j * 16 + l16;
            b[j] = *(const s16x8*)((const char*)Bsm + row * 64 + quad * 16);
        }
#pragma unroll
        for (int i = 0; i < 4; i++)
#pragma unroll
            for (int j = 0; j < 4; j++)
                acc[i][j] = __builtin_amdgcn_mfma_f32_16x16x32_bf16(a[i], b[j], acc[i][j], 0, 0, 0);
    }

    if (mode == 3) {
        // V^T epilogue: transpose 128x128 tile through LDS (XOR-swizzled),
        // then coalesced 16B row stores.
        ushort* T = Asm;
        const int b_ = m0 >> 11;
        const int s_base = m0 & 2047;
        __syncthreads();
#pragma unroll
        for (int half = 0; half < 2; ++half) {
            if (wn == half) {
#pragma unroll
                for (int j = 0; j < 4; j++) {
                    int nl = j * 16 + l16;
                    float bv = bia[n0 + half * 64 + nl];
#pragma unroll
                    for (int i = 0; i < 4; i++) {
#pragma unroll
                        for (int r = 0; r < 4; r++) {
                            int ml = wm * 64 + i * 16 + quad * 4 + r;
                            T[nl * 128 + (ml ^ ((nl & 15) << 3))] = f2bf(acc[i][j][r] + bv);
                        }
                    }
                }
            }
            __syncthreads();
            {
                int row = t >> 2, cg = (t & 3) * 32;
                int ng = n0 + half * 64 + row;
                int h = ng >> 6, d = ng & 63;
                ushort* op = (ushort*)out + ((size_t)((b_ * 16 + h) * 64 + d)) * 2048 + s_base + cg;
#pragma unroll
                for (int c = 0; c < 4; c++) {
                    int col = (cg + c * 8) ^ ((row & 15) << 3);
                    *(s16x8*)(op + c * 8) = *(const s16x8*)(T + row * 128 + col);
                }
            }
            __syncthreads();
        }
        return;
    }

#pragma unroll
    for (int j = 0; j < 4; j++) {
        int n = n0 + wn * 64 + j * 16 + l16;
        float bv = bia[n];
#pragma unroll
        for (int i = 0; i < 4; i++) {
#pragma unroll
            for (int r = 0; r < 4; r++) {
                int m = m0 + wm * 64 + i * 16 + quad * 4 + r;
                float v = acc[i][j][r] + bv;
                if (mode == 0) {
                    ((float*)out)[(size_t)m * 1024 + n] = v;
                } else {
                    int b_ = m >> 11, s = m & 2047;
                    int h = n >> 6, d = n & 63;
                    if (mode == 1)  // 0.125 * log2(e): attn softmax runs in exp2 domain
                        ((ushort*)out)[((size_t)(b_ * 16 + h) * 2048 + s) * 64 + d] = f2bf(v * 0.18033688011112042f);
                    else
                        ((ushort*)out)[((size_t)(b_ * 16 + h) * 2048 + s) * 64 + d] = f2bf(v);
                }
            }
        }
    }
}

// ---------------- MFMA flash attention: LDS-staged 2-phase pipeline ----------
// grid: 512 flat (bijective XCD swizzle, 4 bh/XCD), 256 threads = 4 waves.
// Each wave owns 32 q-rows (block = 128); all 4 waves SHARE each K/V tile
// (64 k-rows, 8KB+8KB) staged via async global_load_lds, double-buffered:
//   per tile: issue next-tile gld16 -> compute current from LDS -> barrier.
// LDS layout linear [row][8 chunks x 16B] with SOURCE chunk-XOR (chunk^=row&7,
// m173 pattern): global staging stays coalesced (XOR permutes within each
// 128B row-segment); ds_read_b128 frags at chunk ((2c+hi)^(l32&7)) touch all
// 32 banks uniformly -> zero conflict.
// Math (verified R2-R4): St = mfma(K,Q) -> lane holds col q=lane&31;
// P pack via cvt_pk + permlane32_swap; O^T = mfma(Vt,P^T); exp2 domain.
#define MFMA32(a, b, c) __builtin_amdgcn_mfma_f32_32x32x16_bf16(a, b, c, 0, 0, 0)

__global__ __launch_bounds__(256, 2) void attn(const ushort* __restrict__ q_ws,
                                               const ushort* __restrict__ k_ws,
                                               const ushort* __restrict__ vt_ws,
                                               ushort* __restrict__ ctx) {
    __shared__ __align__(16) ushort Kb[2][4096];   // 8KB per buffer
    __shared__ __align__(16) ushort Vb[2][4096];
    __shared__ ushort obuf[4][32][72];             // bf16 epilogue transpose

    const int t = threadIdx.x, lane = t & 63, w = t >> 6;
    const int l32 = lane & 31, hi = lane >> 5;

    // bijective XCD swizzle: 512 blocks, 64 per XCD, 4 bh per XCD
    const int bid = blockIdx.x;
    const int j_ = bid >> 3;
    const int bh = (bid & 7) + 8 * (j_ >> 4);
    const int q0 = (j_ & 15) * 128 + w * 32;

    const ushort* Qg = q_ws + (size_t)bh * S_ * 64;
    const ushort* Kg = k_ws + (size_t)bh * S_ * 64;
    const ushort* Vg = vt_ws + (size_t)bh * 64 * S_;

    // Q fragments: B-operand of QK^T. col=lane&31 -> q=q0+l32; k=8*hi+e -> d.
    s16x8 qf[4];
#pragma unroll
    for (int dc = 0; dc < 4; dc++)
        qf[dc] = *(const s16x8*)&Qg[(size_t)(q0 + l32) * 64 + dc * 16 + hi * 8];

    // staging sources: thread t covers slots t (rows 0..31) and t+256 (rows 32..63)
    // slot i: row=i>>3, chunk=i&7; source chunk' = chunk ^ (row&7)
    const int sr = t >> 3;
    const int sc = (t & 7) ^ (sr & 7);
    const ushort* kS = Kg + sr * 64 + sc * 8;            // + kt*4096
    const ushort* vS = Vg + (size_t)sr * 2048 + sc * 8;  // + kt*64
    ushort* ldsK0 = &Kb[0][w * 512];                     // wave-uniform dests
    ushort* ldsV0 = &Vb[0][w * 512];
    ushort* ldsK1 = &Kb[1][w * 512];
    ushort* ldsV1 = &Vb[1][w * 512];

    // frag read offsets (ushorts): row l32, chunk ((c<<1)|hi) ^ (l32&7); sub1 = +2048
    int fo[4];
#pragma unroll
    for (int c = 0; c < 4; c++)
        fo[c] = l32 * 64 + ((((c << 1) | hi) ^ (l32 & 7)) << 3);

    const f32x16 Z16 = {0.f,0.f,0.f,0.f,0.f,0.f,0.f,0.f,0.f,0.f,0.f,0.f,0.f,0.f,0.f,0.f};
    f32x16 o0 = Z16, o1 = Z16;            // O^T: o0 = d 0..31, o1 = d 32..63
    float m_run = -1e30f, l_run = 0.f;

    // prologue: stage tile 0 into buffer 0
    gld16(ldsK0,        kS);
    gld16(ldsK0 + 2048, kS + 2048);       // rows 32..63 (same chunk XOR)
    gld16(ldsV0,        vS);
    gld16(ldsV0 + 2048, vS + (size_t)32 * 2048);
    __syncthreads();

    for (int kt = 0; kt < S_ / 64; ++kt) {
        const int cur = kt & 1;
        if (kt != S_ / 64 - 1) {          // issue next-tile staging (async)
            const ushort* kn = kS + (kt + 1) * 4096;
            const ushort* vn = vS + (kt + 1) * 64;
            ushort* dK = cur ? ldsK0 : ldsK1;
            ushort* dV = cur ? ldsV0 : ldsV1;
            gld16(dK,        kn);
            gld16(dK + 2048, kn + 2048);
            gld16(dV,        vn);
            gld16(dV + 2048, vn + (size_t)32 * 2048);
        }
        const ushort* KB = &Kb[cur][0];
        const ushort* VB = &Vb[cur][0];

        // ---- QK^T from LDS: s0 = k-rows 0..31, s1 = rows 32..63
        f32x16 s0 = Z16, s1 = Z16;
#pragma unroll
        for (int dc = 0; dc < 4; dc++) {
            s16x8 k0 = *(const s16x8*)(KB + fo[dc]);
            s16x8 k1 = *(const s16x8*)(KB + 2048 + fo[dc]);
            s0 = MFMA32(k0, qf[dc], s0);
            s1 = MFMA32(k1, qf[dc], s1);
        }

        // ---- online softmax (exp2 domain), 4-chain max tree
        float m0 = fmaxf(s0[0], s1[0]), m1 = fmaxf(s0[1], s1[1]);
        float m2 = fmaxf(s0[2], s1[2]), m3 = fmaxf(s0[3], s1[3]);
#pragma unroll
        for (int r = 4; r < 16; r += 4) {
            m0 = fmaxf(m0, fmaxf(s0[r],     s1[r]));
            m1 = fmaxf(m1, fmaxf(s0[r + 1], s1[r + 1]));
            m2 = fmaxf(m2, fmaxf(s0[r + 2], s1[r + 2]));
            m3 = fmaxf(m3, fmaxf(s0[r + 3], s1[r + 3]));
        }
        float mx = fmaxf(fmaxf(m0, m1), fmaxf(m2, m3));
        mx = xmax32(mx);
        float mnew = fmaxf(m_run, mx);
        float alpha = exp2_fast(m_run - mnew);
        m_run = mnew;

        float ra = 0.f, rb = 0.f;
#pragma unroll
        for (int r = 0; r < 16; r++) {
            s0[r] = exp2_fast(s0[r] - mnew); ra += s0[r];
            s1[r] = exp2_fast(s1[r] - mnew); rb += s1[r];
        }
        l_run = l_run * alpha + xadd32(ra + rb);

#pragma unroll
        for (int r = 0; r < 16; r++) { o0[r] *= alpha; o1[r] *= alpha; }

        // ---- PV: O^T += Vt x P^T (pack verified R4). ks block uses kc=2ks,2ks+1.
#pragma unroll
        for (int ks = 0; ks < 2; ks++) {
            const f32x16& p = ks ? s1 : s0;
            uint32_t u0 = cvtpk(p[0], p[1]),   u2 = cvtpk(p[4], p[5]);
            plswap(u0, u2);
            uint32_t u1 = cvtpk(p[2], p[3]),   u3 = cvtpk(p[6], p[7]);
            plswap(u1, u3);
            uint32_t w0 = cvtpk(p[8], p[9]),   w2 = cvtpk(p[12], p[13]);
            plswap(w0, w2);
            uint32_t w1 = cvtpk(p[10], p[11]), w3 = cvtpk(p[14], p[15]);
            plswap(w1, w3);
            union { uint32_t u[4]; s16x8 h; } F0, F1;
            F0.u[0] = u0; F0.u[1] = u1; F0.u[2] = u2; F0.u[3] = u3;
            F1.u[0] = w0; F1.u[1] = w1; F1.u[2] = w2; F1.u[3] = w3;

            const int kc0 = ks * 2, kc1 = ks * 2 + 1;
            s16x8 v00 = *(const s16x8*)(VB + fo[kc0]);
            s16x8 v01 = *(const s16x8*)(VB + 2048 + fo[kc0]);
            s16x8 v10 = *(const s16x8*)(VB + fo[kc1]);
            s16x8 v11 = *(const s16x8*)(VB + 2048 + fo[kc1]);
            o0 = MFMA32(v00, F0.h, o0); o1 = MFMA32(v01, F0.h, o1);
            o0 = MFMA32(v10, F1.h, o0); o1 = MFMA32(v11, F1.h, o1);
        }

        __syncthreads();  // drains vmcnt (next tile staged) + lgkm; swap buffers
    }

    // ---- epilogue: O^T -> per-wave LDS transpose (bf16) -> 16B row stores
    float inv = 1.0f / l_run;
#pragma unroll
    for (int r = 0; r < 16; r++) {
        int d0 = (r & 3) + 8 * (r >> 2) + 4 * hi;
        obuf[w][l32][d0]      = f2bf(o0[r] * inv);
        obuf[w][l32][32 + d0] = f2bf(o1[r] * inv);
    }
    // obuf[w] is wave-private: wave-level LDS drain suffices
    asm volatile("s_waitcnt lgkmcnt(0)" ::: "memory");
    __builtin_amdgcn_sched_barrier(0);
    int b_ = bh >> 4, h = bh & 15;
    ushort* gp = ctx + ((size_t)(b_ * 2048 + q0 + l32)) * 1024 + h * 64 + hi * 32;
#pragma unroll
    for (int c = 0; c < 4; c++)
        *(s16x8*)(gp + c * 8) = *(const s16x8*)&obuf[w][l32][hi * 32 + c * 8];
}

extern "C" void kernel_launch(void* const* d_in, const int* in_sizes, int n_in,
                              void* d_out, int out_size, void* d_ws, size_t ws_size,
                              hipStream_t stream) {
    const float* X  = (const float*)d_in[0];
    const float* Wq = (const float*)d_in[1];
    const float* bq = (const float*)d_in[2];
    const float* Wk = (const float*)d_in[3];
    const float* bk = (const float*)d_in[4];
    const float* Wv = (const float*)d_in[5];
    const float* bv = (const float*)d_in[6];
    const float* Wo = (const float*)d_in[7];
    const float* bo = (const float*)d_in[8];
    float* out = (float*)d_out;

    // ws (MiB): wtq@0(2) wtk@2(2) wtv@4(2) wto@6(2) qws@8(8) kws@16(8)
    // ctx@24(8) = 32 MiB. d_out (16 MiB fp32) hosts V^T bf16 @0 (8 MiB) and
    // Xbf16 @8MiB (8 MiB): both dead before the final GEMM overwrites d_out.
    char* ws = (char*)d_ws;
    ushort* wtq  = (ushort*)(ws);
    ushort* wtk  = (ushort*)(ws + ((size_t)2 << 20));
    ushort* wtv  = (ushort*)(ws + ((size_t)4 << 20));
    ushort* wto  = (ushort*)(ws + ((size_t)6 << 20));
    ushort* qws  = (ushort*)(ws + ((size_t)8 << 20));
    ushort* kws  = (ushort*)(ws + ((size_t)16 << 20));
    ushort* ctx  = (ushort*)(ws + ((size_t)24 << 20));
    ushort* vtws = (ushort*)d_out;
    ushort* xbf  = (ushort*)d_out + ((size_t)4 << 20);  // +8 MiB

    transpose_k4<<<dim3(32, 32, 4), dim3(32, 8), 0, stream>>>(Wq, Wk, Wv, Wo,
                                                              wtq, wtk, wtv, wto);
    cast_bf16<<<2048, 256, 0, stream>>>(X, xbf);

    gemm_bt<<<dim3(8, 32, 3), 256, 0, stream>>>(xbf, wtq, wtk, wtv, bq, bk, bv,
                                                qws, kws, vtws, 1);

    attn<<<dim3(512), 256, 0, stream>>>(qws, kws, vtws, ctx);

    gemm_bt<<<dim3(8, 32, 1), 256, 0, stream>>>(ctx, wto, wto, wto, bo, bo, bo,
                                                out, out, out, 0);
}